// Round 5
// baseline (215.858 us; speedup 1.0000x reference)
//
#include <hip/hip_runtime.h>

// ---------- types ----------
typedef unsigned short u16;
typedef __bf16 bf16x8 __attribute__((ext_vector_type(8)));
typedef float f32x4 __attribute__((ext_vector_type(4)));
typedef float f32x16 __attribute__((ext_vector_type(16)));
typedef float float4v __attribute__((ext_vector_type(4)));
typedef unsigned short u16x8 __attribute__((ext_vector_type(8)));
typedef unsigned short u16x4 __attribute__((ext_vector_type(4)));

#define MFMA16(a, b, c) __builtin_amdgcn_mfma_f32_16x16x32_bf16(a, b, c, 0, 0, 0)
#define MFMA32(a, b, c) __builtin_amdgcn_mfma_f32_32x32x16_bf16(a, b, c, 0, 0, 0)

__device__ __forceinline__ u16 f2bf(float f) {
  union { float f; unsigned u; } v; v.f = f;
  unsigned r = v.u + 0x7fffu + ((v.u >> 16) & 1u);
  return (u16)(r >> 16);
}
__device__ __forceinline__ float bf2f(u16 b) {
  union { unsigned u; float f; } v; v.u = ((unsigned)b) << 16;
  return v.f;
}

// async global->LDS, 16B per lane; LDS dest must be wave-uniform base + lane*16
__device__ __forceinline__ void gload16(const void* g, void* l) {
  __builtin_amdgcn_global_load_lds(
      (__attribute__((address_space(1))) void*)g,
      (__attribute__((address_space(3))) void*)l, 16, 0, 0);
}

__device__ __forceinline__ unsigned cvtpk(float lo, float hi) {
  unsigned r;
  asm("v_cvt_pk_bf16_f32 %0, %1, %2" : "=v"(r) : "v"(lo), "v"(hi));
  return r;
}
// swap a.lanes[32:63] <-> b.lanes[0:31]
__device__ __forceinline__ void plswap(unsigned& a, unsigned& b) {
  asm volatile("v_permlane32_swap_b32 %0, %1" : "+v"(a), "+v"(b));
}

// ---------- kernel 1: fp32 -> bf16 weight conversions (x handled in gemm_h) ----------
__global__ __launch_bounds__(256) void convert_w(
    const float* __restrict__ cw,
    const float* __restrict__ tw, const float* __restrict__ pw,
    const float* __restrict__ gw, const float* __restrict__ fw,
    const float* __restrict__ tb, const float* __restrict__ pb,
    const float* __restrict__ gb,
    u16* __restrict__ cwb, u16* __restrict__ wcat, u16* __restrict__ fwb,
    float* __restrict__ bcat) {
  const int idx = blockIdx.x * 256 + threadIdx.x;  // f32x4 units
  const float* src;
  u16* dst;
  int off;
  if (idx < 16384)      { src = cw; dst = cwb;  off = idx; }
  else if (idx < 32768) { src = tw; dst = wcat; off = idx - 16384; }
  else if (idx < 49152) { src = pw; dst = wcat + 65536;  off = idx - 32768; }
  else if (idx < 65536) { src = gw; dst = wcat + 131072; off = idx - 49152; }
  else if (idx < 81920) { src = fw; dst = fwb;  off = idx - 65536; }
  else if (idx < 82112) {
    int j = (idx - 81920) * 4;
#pragma unroll
    for (int i = 0; i < 4; ++i) {
      int k = j + i;
      bcat[k] = (k < 256) ? tb[k] : (k < 512) ? pb[k - 256] : gb[k - 512];
    }
    return;
  } else return;
  float4v v = *(const float4v*)(src + (size_t)off * 4);
  u16x4 o;
#pragma unroll
  for (int i = 0; i < 4; ++i) o[i] = f2bf(v[i]);
  *(u16x4*)(dst + (size_t)off * 4) = o;
}

// ---------- kernel 2: plain bf16 GEMM (tpg), C[m][n] = A[m][:]·W[n][:] + bias[n] ----------
__global__ __launch_bounds__(256) void gemm_bt(
    const u16* __restrict__ A, const u16* __restrict__ W,
    const float* __restrict__ bias, u16* __restrict__ Cout, int K, int ldc) {
  __shared__ u16 As[8192];
  __shared__ u16 Bs[8192];
  const int t = threadIdx.x;
  const int lane = t & 63, w = t >> 6;
  const int brow = blockIdx.x * 128, bcol = blockIdx.y * 128;
  const int wr = (w >> 1) * 64, wc = (w & 1) * 64;
  f32x4 acc[4][4];
#pragma unroll
  for (int i = 0; i < 4; ++i)
#pragma unroll
    for (int j = 0; j < 4; ++j)
#pragma unroll
      for (int r = 0; r < 4; ++r) acc[i][j][r] = 0.0f;

  const int sr = t >> 3, sc8 = (t & 7) * 8;
  const u16* gA = A + (size_t)(brow + sr) * K + sc8;
  const u16* gW = W + (size_t)(bcol + sr) * K + sc8;

  for (int kt = 0; kt < K; kt += 64) {
#pragma unroll
    for (int c = 0; c < 4; ++c) {
      gload16(gA + (size_t)c * 32 * K + kt, &As[c * 2048 + t * 8]);
      gload16(gW + (size_t)c * 32 * K + kt, &Bs[c * 2048 + t * 8]);
    }
    __syncthreads();
#pragma unroll
    for (int kk = 0; kk < 2; ++kk) {
      const int ko = kk * 32 + (lane >> 4) * 8;
      bf16x8 af[4], bfr[4];
#pragma unroll
      for (int i = 0; i < 4; ++i)
        af[i] = *(const bf16x8*)(&As[(wr + i * 16 + (lane & 15)) * 64 + ko]);
#pragma unroll
      for (int j = 0; j < 4; ++j)
        bfr[j] = *(const bf16x8*)(&Bs[(wc + j * 16 + (lane & 15)) * 64 + ko]);
#pragma unroll
      for (int i = 0; i < 4; ++i)
#pragma unroll
        for (int j = 0; j < 4; ++j)
          acc[i][j] = MFMA16(af[i], bfr[j], acc[i][j]);
    }
    __syncthreads();
  }

  const int r0 = (lane >> 4) * 4, c0 = lane & 15;
#pragma unroll
  for (int i = 0; i < 4; ++i)
#pragma unroll
    for (int j = 0; j < 4; ++j) {
      const int col = bcol + wc + j * 16 + c0;
      const float bv = bias[col];
#pragma unroll
      for (int r = 0; r < 4; ++r) {
        const size_t o = (size_t)(brow + wr + i * 16 + r0 + r) * ldc + col;
        Cout[o] = f2bf(acc[i][j][r] + bv);
      }
    }
}

// ---------- kernel 2b: h-GEMM with fused f32->bf16 A conversion ----------
// A = x (f32, K=256); staged via reg-cvt into XOR-swizzled As (unit ^= row&7).
__global__ __launch_bounds__(256) void gemm_h(
    const float* __restrict__ X, const u16* __restrict__ W,
    const float* __restrict__ bias, u16* __restrict__ Cout) {
  __shared__ u16 As[8192];
  __shared__ u16 Bs[8192];
  const int t = threadIdx.x;
  const int lane = t & 63, w = t >> 6;
  const int brow = blockIdx.x * 128, bcol = blockIdx.y * 128;
  const int wr = (w >> 1) * 64, wc = (w & 1) * 64;
  f32x4 acc[4][4];
#pragma unroll
  for (int i = 0; i < 4; ++i)
#pragma unroll
    for (int j = 0; j < 4; ++j)
#pragma unroll
      for (int r = 0; r < 4; ++r) acc[i][j][r] = 0.0f;

  const int sr = t >> 3, sc8 = (t & 7) * 8;
  const u16* gW = W + (size_t)(bcol + sr) * 256 + sc8;
  const int ar = t & 127, ach = t >> 7;  // A staging: row, col-half
  const float* gX = X + (size_t)(brow + ar) * 256 + ach * 32;

  for (int kt = 0; kt < 256; kt += 64) {
    // B: async to LDS (linear)
#pragma unroll
    for (int c = 0; c < 4; ++c)
      gload16(gW + (size_t)c * 32 * 256 + kt, &Bs[c * 2048 + t * 8]);
    // A: f32 load -> cvt -> swizzled ds_write
    u16x8 pk[4];
#pragma unroll
    for (int j = 0; j < 4; ++j) {
      float4v v0 = *(const float4v*)(gX + kt + j * 8);
      float4v v1 = *(const float4v*)(gX + kt + j * 8 + 4);
#pragma unroll
      for (int e = 0; e < 4; ++e) { pk[j][e] = f2bf(v0[e]); pk[j][4 + e] = f2bf(v1[e]); }
    }
#pragma unroll
    for (int j = 0; j < 4; ++j) {
      int unit = (ach * 4 + j) ^ (ar & 7);
      *(u16x8*)(&As[ar * 64 + unit * 8]) = pk[j];
    }
    __syncthreads();
#pragma unroll
    for (int kk = 0; kk < 2; ++kk) {
      const int ko = kk * 32 + (lane >> 4) * 8;
      bf16x8 af[4], bfr[4];
#pragma unroll
      for (int i = 0; i < 4; ++i) {
        int R = wr + i * 16 + (lane & 15);
        int unit = (kk * 4 + (lane >> 4)) ^ (R & 7);
        af[i] = *(const bf16x8*)(&As[R * 64 + unit * 8]);
      }
#pragma unroll
      for (int j = 0; j < 4; ++j)
        bfr[j] = *(const bf16x8*)(&Bs[(wc + j * 16 + (lane & 15)) * 64 + ko]);
#pragma unroll
      for (int i = 0; i < 4; ++i)
#pragma unroll
        for (int j = 0; j < 4; ++j)
          acc[i][j] = MFMA16(af[i], bfr[j], acc[i][j]);
    }
    __syncthreads();
  }

  const int r0 = (lane >> 4) * 4, c0 = lane & 15;
#pragma unroll
  for (int i = 0; i < 4; ++i)
#pragma unroll
    for (int j = 0; j < 4; ++j) {
      const int col = bcol + wc + j * 16 + c0;
      const float bv = bias[col];
#pragma unroll
      for (int r = 0; r < 4; ++r) {
        const size_t o = (size_t)(brow + wr + i * 16 + r0 + r) * 256 + col;
        Cout[o] = f2bf(acc[i][j][r] + bv);
      }
    }
}

// ---------- kernel 3: transpose g -> gT[b][k][m] ----------
__global__ __launch_bounds__(256) void transpose_g_k(
    const u16* __restrict__ tpg, u16* __restrict__ gT) {
  __shared__ u16 T[64][65];
  const int t = threadIdx.x;
  const int bm = (blockIdx.x & 63) * 64;
  const int bk = ((blockIdx.x >> 6) & 3) * 64;
  const int b = blockIdx.x >> 8;
  const int r = t >> 3, c8 = (t & 7) * 8;
#pragma unroll
  for (int ch = 0; ch < 2; ++ch) {
    u16x8 v = *(const u16x8*)(tpg + (size_t)(b * 4096 + bm + r + ch * 32) * 768 + 512 + bk + c8);
#pragma unroll
    for (int j = 0; j < 8; ++j) T[r + ch * 32][c8 + j] = v[j];
  }
  __syncthreads();
#pragma unroll
  for (int ch = 0; ch < 2; ++ch) {
    u16x8 o;
#pragma unroll
    for (int j = 0; j < 8; ++j) o[j] = T[c8 + j][r + ch * 32];
    *(u16x8*)(gT + (size_t)(b * 256 + bk + r + ch * 32) * 4096 + bm + c8) = o;
  }
}

// ---------- kernel 4: flash attention v3 (v2 + T5 setprio, Lp as bf16) ----------
__global__ __launch_bounds__(256, 2) void flash2(
    const u16* __restrict__ tpg, const u16* __restrict__ gT,
    u16* __restrict__ Zp, u16* __restrict__ Lpb) {
  __shared__ u16 Kl[2][32 * 256];  // rows=kv(32), swz c16^row
  __shared__ u16 Vl[2][256 * 32];  // rows=d(256), swz c16^((row>>1)&3)

  const int t = threadIdx.x;
  const int lane = t & 63, w = t >> 6;
  const int l31 = lane & 31, hi = lane >> 5;
  const int bid = blockIdx.x;
  const int b = bid >> 7;
  const int quarter = (bid >> 5) & 3;
  const int qt = bid & 31;
  const int q0 = qt * 128 + w * 32;
  const int kv0 = quarter * 1024;

  bf16x8 q[16];
  {
    const u16* qp = tpg + (size_t)(b * 4096 + q0 + l31) * 768 + hi * 8;
#pragma unroll
    for (int ks = 0; ks < 16; ++ks) q[ks] = *(const bf16x8*)(qp + ks * 16);
  }

  f32x16 zacc[8];
#pragma unroll
  for (int i = 0; i < 8; ++i)
#pragma unroll
    for (int j = 0; j < 16; ++j) zacc[i][j] = 0.0f;
  float ell = 0.0f;

  const int ksr = t >> 5, ksc = t & 31;

  auto stage = [&](int tile, int bi) {
    const size_t krow0 = (size_t)(b * 4096 + kv0 + tile * 32);
#pragma unroll
    for (int ch = 0; ch < 4; ++ch) {
      int r = ch * 8 + ksr;
      gload16(tpg + (krow0 + r) * 768 + 256 + ((ksc ^ r) * 8), &Kl[bi][ch * 2048 + t * 8]);
    }
#pragma unroll
    for (int ch = 0; ch < 4; ++ch) {
      int u = ch * 256 + t;
      int r = u >> 2, c16 = u & 3;
      gload16(gT + (size_t)(b * 256 + r) * 4096 + kv0 + tile * 32 + ((c16 ^ ((r >> 1) & 3)) * 8),
              &Vl[bi][u * 8]);
    }
  };

  stage(0, 0);
  __syncthreads();

  for (int tile = 0; tile < 32; ++tile) {
    const int cur = tile & 1;
    if (tile + 1 < 32) stage(tile + 1, cur ^ 1);

    // S^T = K * Q^T
    f32x16 s;
#pragma unroll
    for (int j = 0; j < 16; ++j) s[j] = 0.0f;
    const u16* kb = &Kl[cur][0];
    __builtin_amdgcn_s_setprio(1);
#pragma unroll
    for (int ks = 0; ks < 16; ++ks) {
      bf16x8 kf = *(const bf16x8*)(kb + l31 * 256 + (((2 * ks + hi) ^ l31) * 8));
      s = MFMA32(kf, q[ks], s);
    }
    __builtin_amdgcn_s_setprio(0);

    // in-register softmax numerators -> PV A-frags
    bf16x8 pa[2];
#pragma unroll
    for (int half = 0; half < 2; ++half) {
      float p[8];
#pragma unroll
      for (int g = 0; g < 8; ++g) {
        p[g] = __builtin_amdgcn_exp2f(s[half * 8 + g] * 0.09016844f);
        ell += p[g];
      }
      unsigned x0 = cvtpk(p[0], p[1]), y0 = cvtpk(p[4], p[5]);
      unsigned x1 = cvtpk(p[2], p[3]), y1 = cvtpk(p[6], p[7]);
      plswap(x0, y0);
      plswap(x1, y1);
      union { unsigned u[4]; bf16x8 v; } cc;
      cc.u[0] = x0; cc.u[1] = x1; cc.u[2] = y0; cc.u[3] = y1;
      pa[half] = cc.v;
    }

    // Z += P * V
    const u16* vb = &Vl[cur][0];
    __builtin_amdgcn_s_setprio(1);
#pragma unroll
    for (int ks2 = 0; ks2 < 2; ++ks2) {
#pragma unroll
      for (int nt = 0; nt < 8; ++nt) {
        int row = nt * 32 + l31;
        bf16x8 vv = *(const bf16x8*)(vb + row * 32 + (((2 * ks2 + hi) ^ ((row >> 1) & 3)) * 8));
        zacc[nt] = MFMA32(pa[ks2], vv, zacc[nt]);
      }
    }
    __builtin_amdgcn_s_setprio(0);
    __syncthreads();
  }

  ell += __shfl_xor(ell, 32, 64);

#pragma unroll
  for (int g = 0; g < 16; ++g) {
    int r = (g & 3) + 8 * (g >> 2) + 4 * hi;
    size_t rowoff = ((size_t)(quarter * 16384 + b * 4096 + q0 + r)) * 256 + l31;
#pragma unroll
    for (int nt = 0; nt < 8; ++nt) Zp[rowoff + nt * 32] = f2bf(zacc[nt][g]);
  }
  if (lane < 32) Lpb[quarter * 16384 + b * 4096 + q0 + l31] = f2bf(ell);
}

// ---------- kernel 5: final GEMM with fused merge/normalize + residual ----------
// A = z = (sum of 4 bf16 Zp partials) / (64 * sum Lp); out = z·fw^T + fb + x (f32)
__global__ __launch_bounds__(256) void gemm_out(
    const u16* __restrict__ Zp, const u16* __restrict__ Lpb,
    const u16* __restrict__ W, const float* __restrict__ bias,
    float* __restrict__ Cout, const float* __restrict__ res) {
  __shared__ u16 As[8192];
  __shared__ u16 Bs[8192];
  const int t = threadIdx.x;
  const int lane = t & 63, w = t >> 6;
  const int brow = blockIdx.x * 128, bcol = blockIdx.y * 128;
  const int wr = (w >> 1) * 64, wc = (w & 1) * 64;
  f32x4 acc[4][4];
#pragma unroll
  for (int i = 0; i < 4; ++i)
#pragma unroll
    for (int j = 0; j < 4; ++j)
#pragma unroll
      for (int r = 0; r < 4; ++r) acc[i][j][r] = 0.0f;

  const int sr = t >> 3, sc8 = (t & 7) * 8;
  const u16* gW = W + (size_t)(bcol + sr) * 256 + sc8;
  const int ar = t >> 1, ach = t & 1;  // A staging: row 0..127, col-half
  const int am = brow + ar;
  const float linv = 1.0f /
      ((bf2f(Lpb[am]) + bf2f(Lpb[16384 + am]) + bf2f(Lpb[32768 + am]) + bf2f(Lpb[49152 + am])) *
       64.0f);

  for (int kt = 0; kt < 256; kt += 64) {
#pragma unroll
    for (int c = 0; c < 4; ++c)
      gload16(gW + (size_t)c * 32 * 256 + kt, &Bs[c * 2048 + t * 8]);
    // A: merge 4 partials -> normalize -> bf16 -> swizzled ds_write
    const int col0 = kt + ach * 32;
    float sacc[32];
#pragma unroll
    for (int e = 0; e < 32; ++e) sacc[e] = 0.0f;
#pragma unroll
    for (int qd = 0; qd < 4; ++qd) {
      const u16* zp = Zp + ((size_t)(qd * 16384) + am) * 256 + col0;
#pragma unroll
      for (int j = 0; j < 4; ++j) {
        u16x8 v = *(const u16x8*)(zp + j * 8);
#pragma unroll
        for (int e = 0; e < 8; ++e) sacc[j * 8 + e] += bf2f(v[e]);
      }
    }
#pragma unroll
    for (int j = 0; j < 4; ++j) {
      u16x8 pk;
#pragma unroll
      for (int e = 0; e < 8; ++e) pk[e] = f2bf(sacc[j * 8 + e] * linv);
      int unit = (ach * 4 + j) ^ (ar & 7);
      *(u16x8*)(&As[ar * 64 + unit * 8]) = pk;
    }
    __syncthreads();
#pragma unroll
    for (int kk = 0; kk < 2; ++kk) {
      const int ko = kk * 32 + (lane >> 4) * 8;
      bf16x8 af[4], bfr[4];
#pragma unroll
      for (int i = 0; i < 4; ++i) {
        int R = wr + i * 16 + (lane & 15);
        int unit = (kk * 4 + (lane >> 4)) ^ (R & 7);
        af[i] = *(const bf16x8*)(&As[R * 64 + unit * 8]);
      }
#pragma unroll
      for (int j = 0; j < 4; ++j)
        bfr[j] = *(const bf16x8*)(&Bs[(wc + j * 16 + (lane & 15)) * 64 + ko]);
#pragma unroll
      for (int i = 0; i < 4; ++i)
#pragma unroll
        for (int j = 0; j < 4; ++j)
          acc[i][j] = MFMA16(af[i], bfr[j], acc[i][j]);
    }
    __syncthreads();
  }

  const int r0 = (lane >> 4) * 4, c0 = lane & 15;
#pragma unroll
  for (int i = 0; i < 4; ++i)
#pragma unroll
    for (int j = 0; j < 4; ++j) {
      const int col = bcol + wc + j * 16 + c0;
      const float bv = bias[col];
#pragma unroll
      for (int r = 0; r < 4; ++r) {
        const size_t o = (size_t)(brow + wr + i * 16 + r0 + r) * 256 + col;
        Cout[o] = acc[i][j][r] + bv + res[o];
      }
    }
}

// ---------- launch ----------
extern "C" void kernel_launch(void* const* d_in, const int* in_sizes, int n_in,
                              void* d_out, int out_size, void* d_ws, size_t ws_size,
                              hipStream_t stream) {
  const float* x  = (const float*)d_in[0];
  const float* cw = (const float*)d_in[1];
  const float* cb = (const float*)d_in[2];
  const float* tw = (const float*)d_in[3];
  const float* tb = (const float*)d_in[4];
  const float* pw = (const float*)d_in[5];
  const float* pb = (const float*)d_in[6];
  const float* gw = (const float*)d_in[7];
  const float* gb = (const float*)d_in[8];
  const float* fw = (const float*)d_in[9];
  const float* fb = (const float*)d_in[10];

  char* ws = (char*)d_ws;
  // layout (peak = 67,898,368 B, same as rounds 1-2)
  u16*   tpg  = (u16*)(ws);                   // [16384][768] theta|phi|g   25165824 B
  u16*   gT   = (u16*)(ws + 25165824);        // [4][256][4096]              8388608 B
  u16*   hb   = (u16*)(ws + 41943040);        // dead after tpg-gemm
  u16*   Zp   = (u16*)(ws + 33554432);        // [4][16384][256] bf16, overlaps hb region
  u16*   Lpb  = (u16*)(ws + 67108864);        // [4][16384] bf16, 131072 B
  u16*   cwb  = (u16*)(ws + 67239936);
  u16*   wcat = (u16*)(ws + 67371008);        // [768][256]
  u16*   fwb  = (u16*)(ws + 67764224);
  float* bcat = (float*)(ws + 67895296);      // [768]

  convert_w<<<321, 256, 0, stream>>>(cw, tw, pw, gw, fw, tb, pb, gb,
                                     cwb, wcat, fwb, bcat);
  // h = x @ conv_w^T + conv_b  (f32 A converted in staging)
  gemm_h<<<dim3(128, 2), 256, 0, stream>>>(x, cwb, cb, hb);
  // theta|phi|g = h @ wcat^T + bcat
  gemm_bt<<<dim3(128, 6), 256, 0, stream>>>(hb, wcat, bcat, tpg, 256, 768);
  transpose_g_k<<<1024, 256, 0, stream>>>(tpg, gT);
  flash2<<<512, 256, 0, stream>>>(tpg, gT, Zp, Lpb);
  // out = merge(Zp)/L @ f_w^T + f_b + x
  gemm_out<<<dim3(128, 2), 256, 0, stream>>>(Zp, Lpb, fwb, fb, (float*)d_out, x);
}